// Round 1
// baseline (91.879 us; speedup 1.0000x reference)
//
#include <hip/hip_runtime.h>

#define B_      16
#define S_      65
#define R_      1040
#define W_      256
#define T_      2176
#define D_      128
#define MAXSEQ  2048

// ---------------------------------------------------------------------------
// Kernel 1: per-row offsets + masked counts + exclusive scan (single block).
// mask within a row is a prefix [0, cnt_r) because floor(w/sc) is monotone in w
// and both mask bounds are row-constant. cnt_r computed with IEEE fp32 division
// to match the reference mask bit-exactly.
// ---------------------------------------------------------------------------
__global__ __launch_bounds__(256) void interp_setup(
    const float* __restrict__ scales,
    const int*   __restrict__ len_seq,
    const int*   __restrict__ len_seg_raw,
    int* __restrict__ offs,        // [R_] per-row source offset
    int* __restrict__ row_start,   // [R_+1] exclusive scan of counts
    int* __restrict__ meta)        // [2] total, L
{
    __shared__ int s_len[R_];
    __shared__ int s_off[R_];
    __shared__ int s_cnt[R_];
    const int tid = threadIdx.x;

    for (int r = tid; r < R_; r += 256) s_len[r] = len_seg_raw[r] + 32;  // + MIN_LEN_SEG
    __syncthreads();

    // per-batch exclusive cumsum of segment lengths (16 batches x 65 segs)
    if (tid < B_) {
        int acc = 0, base = tid * S_;
        for (int s = 0; s < S_; ++s) { s_off[base + s] = acc; acc += s_len[base + s]; }
    }
    __syncthreads();

    // per-row masked count: #{ w in [0,256) : fp32(w/sc) < K }, K integer
    for (int r = tid; r < R_; r += 256) {
        float sc  = scales[r] + 0.5f;
        int   off = s_off[r];
        int   K   = min(s_len[r] - 1, len_seq[r / S_] - 1 - off);
        int   c   = 0;
        if (K > 0) {
            c = (int)ceilf((float)K * sc);
            c = min(max(c, 0), W_);
            const float Kf = (float)K;
            while (c > 0  && ((float)(c - 1) / sc) >= Kf) --c;   // exact IEEE div check
            while (c < W_ && ((float)c       / sc) <  Kf) ++c;
        }
        s_cnt[r] = c;
        offs[r]  = off;
    }
    __syncthreads();

    if (tid == 0) {
        int acc = 0;
        for (int r = 0; r < R_; ++r) { row_start[r] = acc; acc += s_cnt[r]; }
        row_start[R_] = acc;
        meta[0] = acc;        // total
        meta[1] = acc / B_;   // L
    }
}

// ---------------------------------------------------------------------------
// Kernel 2: output-driven gather + lerp. 8 output rows per 256-thread block,
// 32 lanes per row (float4 over D=128). Binary search of row_start in LDS.
// ---------------------------------------------------------------------------
__global__ __launch_bounds__(256) void interp_gather(
    const float* __restrict__ x,
    const float* __restrict__ scales,
    const int*   __restrict__ offs,
    const int*   __restrict__ row_start,
    const int*   __restrict__ meta,
    float* __restrict__ out)
{
    __shared__ int s_rs[R_ + 1];
    const int tid = threadIdx.x;
    for (int i = tid; i < R_ + 1; i += 256) s_rs[i] = row_start[i];
    __syncthreads();

    const int L    = meta[1];
    const int orow = blockIdx.x * 8 + (tid >> 5);   // [0, 32768)
    const int lane = tid & 31;
    float4* outp = (float4*)(out + (size_t)orow * D_) + lane;

    const int t = orow & (MAXSEQ - 1);
    const int b = orow >> 11;
    if (t >= L) { *outp = make_float4(0.f, 0.f, 0.f, 0.f); return; }

    const int g = b * L + t;                        // g < total guaranteed
    // largest r with row_start[r] <= g  (invariant: rs[lo] <= g < rs[hi])
    int lo = 0, hi = R_;
    while (hi - lo > 1) {
        int mid = (lo + hi) >> 1;
        if (s_rs[mid] <= g) lo = mid; else hi = mid;
    }
    const int r = lo;
    const int w = g - s_rs[r];

    const float sc  = scales[r] + 0.5f;
    const float is  = (float)w / sc;                // IEEE fp32 div, matches ref
    const float fl  = floorf(is);
    const float lam = is - fl;
    int i0 = (int)fl + offs[r];
    i0 = min(max(i0, 0), T_ - 1);
    const int i1 = min(i0 + 1, T_ - 1);
    const int bs = r / S_;                          // source batch from segment row

    const float* base = x + (size_t)bs * (T_ * D_);
    const float4* pa = (const float4*)(base + (size_t)i0 * D_) + lane;
    const float4* pb = (const float4*)(base + (size_t)i1 * D_) + lane;
    const float4 a = *pa, c = *pb;
    const float om = 1.0f - lam;
    float4 y;
    y.x = om * a.x + lam * c.x;
    y.y = om * a.y + lam * c.y;
    y.z = om * a.z + lam * c.z;
    y.w = om * a.w + lam * c.w;
    *outp = y;
}

extern "C" void kernel_launch(void* const* d_in, const int* in_sizes, int n_in,
                              void* d_out, int out_size, void* d_ws, size_t ws_size,
                              hipStream_t stream) {
    const float* x           = (const float*)d_in[0];  // (16, 2176, 128) f32
    const float* scales      = (const float*)d_in[1];  // (1040,) f32
    const int*   len_seq     = (const int*)d_in[2];    // (16,) i32
    const int*   len_seg_raw = (const int*)d_in[3];    // (1040,1) i32
    float*       out         = (float*)d_out;          // (16, 2048, 128) f32

    int* offs      = (int*)d_ws;        // R_
    int* row_start = offs + R_;         // R_+1
    int* meta      = row_start + R_ + 1;// 2

    interp_setup<<<1, 256, 0, stream>>>(scales, len_seq, len_seg_raw,
                                        offs, row_start, meta);

    const int nrows = B_ * MAXSEQ;      // 32768 output rows
    interp_gather<<<nrows / 8, 256, 0, stream>>>(x, scales, offs, row_start,
                                                 meta, out);
}